// Round 1
// 820.728 us; speedup vs baseline: 1.1459x; 1.1459x over previous
//
#include <hip/hip_runtime.h>
#include <hip/hip_bf16.h>
#include <cstdint>

typedef __hip_bfloat16 bf16;
typedef unsigned int uint;
typedef unsigned short ushort;

#define DEVI __device__ __forceinline__

DEVI float blo(uint u){ return __uint_as_float(u << 16); }
DEVI float bhi(uint u){ return __uint_as_float(u & 0xffff0000u); }
// f32 -> bf16 RTNE (finite inputs)
DEVI ushort f2b(float x){ uint u = __float_as_uint(x); uint r = (u + 0x7fffu + ((u >> 16) & 1u)) >> 16; return (ushort)r; }
DEVI uint pack2(float a, float b){ return (uint)f2b(a) | ((uint)f2b(b) << 16); }
DEVI float b2f(ushort h){ return __uint_as_float((uint)h << 16); }

typedef short bf16x8 __attribute__((ext_vector_type(8)));
typedef float f32x4  __attribute__((ext_vector_type(4)));

// ---------------- K1: M[h][p][m] = sum_j Wq[h][p][j] * Wk[h][m][j], stored Mb[p][h*128+m]
__global__ __launch_bounds__(256) void build_M(const float* __restrict__ Wq, const float* __restrict__ Wk,
                                               float* __restrict__ Mb){
  __shared__ float WkL[128*33];
  __shared__ float WqL[16*33];
  const int t = threadIdx.x;
  const int h = blockIdx.x >> 3, pg = blockIdx.x & 7, p0 = pg*16;
  const float* wk = Wk + (size_t)h*16384;
  const float* wq = Wq + ((size_t)h*128 + p0)*128;
  const int m = t & 127, half = t >> 7;
  float acc[8] = {0,0,0,0,0,0,0,0};
  for (int jc = 0; jc < 4; ++jc){
    __syncthreads();
    #pragma unroll
    for (int i = 0; i < 4; ++i){
      int g = t + 256*i;                 // 1024 float4 groups = 128 x 32
      int mm = g >> 3, j0 = (g & 7)*4;
      float4 v = *(const float4*)(wk + mm*128 + jc*32 + j0);
      float* d = &WkL[mm*33 + j0];
      d[0] = v.x; d[1] = v.y; d[2] = v.z; d[3] = v.w;
    }
    {
      int e = t*2;                       // 512 floats = 16 x 32
      int pr = e >> 5, jj = e & 31;
      float2 v = *(const float2*)(wq + pr*128 + jc*32 + jj);
      WqL[pr*33 + jj] = v.x; WqL[pr*33 + jj + 1] = v.y;
    }
    __syncthreads();
    for (int j = 0; j < 32; ++j){
      float wkv = WkL[m*33 + j];
      #pragma unroll
      for (int r = 0; r < 8; ++r)
        acc[r] = fmaf(WqL[(half*8 + r)*33 + j], wkv, acc[r]);
    }
  }
  #pragma unroll
  for (int r = 0; r < 8; ++r)
    Mb[(size_t)(p0 + half*8 + r)*1024 + h*128 + m] = acc[r];
}

// ---------------- K1b: cvec[h*128+m] = Wk[h][m]·bq[h];  uvec[h*128+p] = Wq[h][p]·bk[h];  sv[h] = bq·bk
__global__ void build_bias(const float* __restrict__ Wq, const float* __restrict__ Wk,
                           const float* __restrict__ bq, const float* __restrict__ bk,
                           float* __restrict__ cvec, float* __restrict__ uvec, float* __restrict__ sv){
  int h = blockIdx.x, m = threadIdx.x;
  const float* wkr = Wk + ((size_t)h*128 + m)*128;
  const float* wqr = Wq + ((size_t)h*128 + m)*128;
  const float* bqr = bq + h*128;
  const float* bkr = bk + h*128;
  float c = 0.f, u = 0.f;
  for (int j = 0; j < 128; ++j){
    c = fmaf(wkr[j], bqr[j], c);
    u = fmaf(wqr[j], bkr[j], u);
  }
  cvec[h*128 + m] = c;
  uvec[h*128 + m] = u;
  if (m == 0){
    float s = 0.f;
    for (int j = 0; j < 128; ++j) s = fmaf(bqr[j], bkr[j], s);
    sv[h] = s;
  }
}

// ---------------- K2: scatter aq[pdg_key[i]] = ast[pdg_value[i]] (f32)
__global__ void scatter_aq(const int* __restrict__ pk, const int* __restrict__ pv,
                           const float* __restrict__ ast, float* __restrict__ aq, int n_map){
  int i = blockIdx.x;
  if (i >= n_map) return;
  int k = pk[i], src = pv[i];
  int lane = threadIdx.x;
  float2 v = *(const float2*)(ast + (size_t)src*128 + 2*lane);
  *(float2*)(aq + (size_t)k*128 + 2*lane) = v;
}

// ---------------- K3: qt[n][c] = sum_p aq[n][p]*Mb[p][c] + cvec[c]   (qt stored bf16)
__global__ __launch_bounds__(256) void qt_gemm(const float* __restrict__ aq, const float* __restrict__ Mb,
                                               const float* __restrict__ cvec, bf16* __restrict__ qt, int N){
  __shared__ float aqL[32*128];
  const int t = threadIdx.x;
  const int n0 = blockIdx.x * 32;
  #pragma unroll
  for (int i = 0; i < 4; ++i){
    int f4 = t + 256*i;
    int r = f4 >> 5, p0 = (f4 & 31)*4;
    int row = n0 + r; if (row >= N) row = N - 1;
    *(float4*)(aqL + r*128 + p0) = *(const float4*)(aq + (size_t)row*128 + p0);
  }
  __syncthreads();
  const int cg = t & 63, rg = t >> 6;
  for (int chunk = 0; chunk < 4; ++chunk){
    const int c0 = chunk*256 + cg*4;
    float4 acc[8];
    #pragma unroll
    for (int r = 0; r < 8; ++r) acc[r] = make_float4(0.f,0.f,0.f,0.f);
    for (int p = 0; p < 128; ++p){
      float4 b4 = *(const float4*)(Mb + (size_t)p*1024 + c0);
      #pragma unroll
      for (int r = 0; r < 8; ++r){
        float a = aqL[(rg*8 + r)*128 + p];
        acc[r].x = fmaf(a, b4.x, acc[r].x);
        acc[r].y = fmaf(a, b4.y, acc[r].y);
        acc[r].z = fmaf(a, b4.z, acc[r].z);
        acc[r].w = fmaf(a, b4.w, acc[r].w);
      }
    }
    float4 cv = *(const float4*)(cvec + c0);
    #pragma unroll
    for (int r = 0; r < 8; ++r){
      int row = n0 + rg*8 + r;
      if (row < N){
        uint2 o;
        o.x = pack2(acc[r].x + cv.x, acc[r].y + cv.y);
        o.y = pack2(acc[r].z + cv.z, acc[r].w + cv.w);
        *(uint2*)(qt + (size_t)row*1024 + c0) = o;
      }
    }
  }
}

// ---------------- K3b: qb[n][h] = aq[n]·uvec[h] + sv[h]
__global__ void qb_kernel(const float* __restrict__ aq, const float* __restrict__ uvec,
                          const float* __restrict__ sv, float* __restrict__ qb){
  int n = blockIdx.x, lane = threadIdx.x;
  int h = lane >> 3, g = lane & 7;
  const float* ar = aq + (size_t)n*128 + g*16;
  const float* ur = uvec + h*128 + g*16;
  float dot = 0.f;
  #pragma unroll
  for (int k = 0; k < 16; ++k) dot = fmaf(ar[k], ur[k], dot);
  dot += __shfl_xor(dot, 1);
  dot += __shfl_xor(dot, 2);
  dot += __shfl_xor(dot, 4);
  if (g == 0) qb[(size_t)n*8 + h] = dot + sv[h];
}

// ---------------- K4: CSR build
__global__ void count_edges(const int* __restrict__ av, int* __restrict__ counts, int E){
  int e = blockIdx.x*256 + threadIdx.x;
  if (e < E) atomicAdd(&counts[av[e]], 1);
}

__global__ void scan_offsets(const int* __restrict__ counts, int* __restrict__ offsets, int N){
  __shared__ int pa[1024];
  __shared__ int pb[1024];
  int t = threadIdx.x;
  int CH = (N + 1023) >> 10;
  int b = t*CH, e = b + CH;
  if (b > N) b = N;
  if (e > N) e = N;
  int s = 0;
  for (int i = b; i < e; ++i) s += counts[i];
  pa[t] = s;
  __syncthreads();
  int* src = pa; int* dst = pb;
  for (int off = 1; off < 1024; off <<= 1){
    int v = src[t];
    if (t >= off) v += src[t - off];
    __syncthreads();
    dst[t] = v;
    __syncthreads();
    int* tmp = src; src = dst; dst = tmp;
  }
  int run = src[t] - s;
  for (int i = b; i < e; ++i){ offsets[i] = run; run += counts[i]; }
  if (t == 1023) offsets[N] = src[1023];
}

__global__ void fill_edges(const int* __restrict__ av, const int* __restrict__ akey,
                           const int* __restrict__ offsets, int* __restrict__ cursor,
                           int* __restrict__ ridx, int E){
  int e = blockIdx.x*256 + threadIdx.x;
  if (e < E){
    int seg = av[e];
    int pos = offsets[seg] + atomicAdd(&cursor[seg], 1);
    ridx[pos] = akey[e];
  }
}

// ---------------- K6: per-segment attention, SINGLE PASS.
__global__ __launch_bounds__(256) void seg_attn(
    const bf16* __restrict__ qt, const float* __restrict__ qb,
    const int* __restrict__ offsets, const int* __restrict__ ridx,
    const float* __restrict__ ast, bf16* __restrict__ ho, int N)
{
  const int wid  = threadIdx.x >> 6;
  const int lane = threadIdx.x & 63;
  const int n = blockIdx.x*4 + wid;
  if (n >= N) return;
  const int beg = offsets[n];
  const int deg = offsets[n+1] - beg;
  const int h = lane >> 3, g = lane & 7;

  const uint4* qp = (const uint4*)(qt + (size_t)n*1024 + h*128 + g*16);
  const uint4 qa = qp[0], qc = qp[1];
  const float4 q0 = make_float4(blo(qa.x), bhi(qa.x), blo(qa.y), bhi(qa.y));
  const float4 q1 = make_float4(blo(qa.z), bhi(qa.z), blo(qa.w), bhi(qa.w));
  const float4 q2 = make_float4(blo(qc.x), bhi(qc.x), blo(qc.y), bhi(qc.y));
  const float4 q3 = make_float4(blo(qc.z), bhi(qc.z), blo(qc.w), bhi(qc.w));
  const float qbv = qb[(size_t)n*8 + h];
  const float isd = 0.08838834764831845f;  // 1/sqrt(128)

  float den = 0.f;
  float4 x0 = make_float4(0,0,0,0), x1 = x0, x2 = x0, x3 = x0;

  float4 vA = make_float4(0,0,0,0), vB = vA, vC = vA, vD = vA;
  if (deg > 0){
    const float4* vp = (const float4*)(ast + (size_t)ridx[beg]*128 + g*16);
    vA = vp[0]; vB = vp[1]; vC = vp[2]; vD = vp[3];
  }
  for (int e = 0; e < deg; ++e){
    const float4 a0 = vA, a1 = vB, a2 = vC, a3 = vD;
    const int e2 = (e + 1 < deg) ? (e + 1) : e;
    const float4* vpn = (const float4*)(ast + (size_t)ridx[beg + e2]*128 + g*16);
    vA = vpn[0]; vB = vpn[1]; vC = vpn[2]; vD = vpn[3];

    float dot = 0.f;
    dot = fmaf(a0.x, q0.x, dot); dot = fmaf(a0.y, q0.y, dot);
    dot = fmaf(a0.z, q0.z, dot); dot = fmaf(a0.w, q0.w, dot);
    dot = fmaf(a1.x, q1.x, dot); dot = fmaf(a1.y, q1.y, dot);
    dot = fmaf(a1.z, q1.z, dot); dot = fmaf(a1.w, q1.w, dot);
    dot = fmaf(a2.x, q2.x, dot); dot = fmaf(a2.y, q2.y, dot);
    dot = fmaf(a2.z, q2.z, dot); dot = fmaf(a2.w, q2.w, dot);
    dot = fmaf(a3.x, q3.x, dot); dot = fmaf(a3.y, q3.y, dot);
    dot = fmaf(a3.z, q3.z, dot); dot = fmaf(a3.w, q3.w, dot);
    dot += __shfl_xor(dot, 1);
    dot += __shfl_xor(dot, 2);
    dot += __shfl_xor(dot, 4);

    const float p = __expf((dot + qbv) * isd);
    den += p;
    x0.x = fmaf(p, a0.x, x0.x); x0.y = fmaf(p, a0.y, x0.y);
    x0.z = fmaf(p, a0.z, x0.z); x0.w = fmaf(p, a0.w, x0.w);
    x1.x = fmaf(p, a1.x, x1.x); x1.y = fmaf(p, a1.y, x1.y);
    x1.z = fmaf(p, a1.z, x1.z); x1.w = fmaf(p, a1.w, x1.w);
    x2.x = fmaf(p, a2.x, x2.x); x2.y = fmaf(p, a2.y, x2.y);
    x2.z = fmaf(p, a2.z, x2.z); x2.w = fmaf(p, a2.w, x2.w);
    x3.x = fmaf(p, a3.x, x3.x); x3.y = fmaf(p, a3.y, x3.y);
    x3.z = fmaf(p, a3.z, x3.z); x3.w = fmaf(p, a3.w, x3.w);
  }
  const float r = (deg > 0) ? (1.f / den) : 0.f;

  uint4 o0, o1;
  o0.x = pack2(x0.x*r, x0.y*r); o0.y = pack2(x0.z*r, x0.w*r);
  o0.z = pack2(x1.x*r, x1.y*r); o0.w = pack2(x1.z*r, x1.w*r);
  o1.x = pack2(x2.x*r, x2.y*r); o1.y = pack2(x2.z*r, x2.w*r);
  o1.z = pack2(x3.x*r, x3.y*r); o1.w = pack2(x3.z*r, x3.w*r);
  uint4* hb = (uint4*)(ho + (size_t)n*1024 + h*128 + g*16);
  hb[0] = o0;
  hb[1] = o1;
}

// ---------------- K5a: pack Wo[1024][128] f32 -> B-fragment-ordered bf16 hi/lo pairs.
// Fragment for (ks, ct): lane l holds B[k][c] with k = ks*32 + (l>>4)*8 + j (j=0..7),
// c = ct*16 + (l&15). Linear uint4 index: ((ks*16 + ct*2 + s)*64 + l), s=0 hi, s=1 lo.
__global__ void wo_pack(const float* __restrict__ Wo, uint4* __restrict__ Wp){
  const int b = blockIdx.x;            // b = ks*8 + ct, 256 blocks
  const int ks = b >> 3, ct = b & 7;
  const int l = threadIdx.x;           // 64
  const int kb = ks*32 + (l >> 4)*8;
  const int c  = ct*16 + (l & 15);
  ushort hi[8], lo[8];
  #pragma unroll
  for (int j = 0; j < 8; ++j){
    float wv = Wo[(size_t)(kb + j)*128 + c];
    ushort hh = f2b(wv);
    hi[j] = hh;
    lo[j] = f2b(wv - b2f(hh));
  }
  uint4 H, L;
  H.x = (uint)hi[0] | ((uint)hi[1] << 16);
  H.y = (uint)hi[2] | ((uint)hi[3] << 16);
  H.z = (uint)hi[4] | ((uint)hi[5] << 16);
  H.w = (uint)hi[6] | ((uint)hi[7] << 16);
  L.x = (uint)lo[0] | ((uint)lo[1] << 16);
  L.y = (uint)lo[2] | ((uint)lo[3] << 16);
  L.z = (uint)lo[4] | ((uint)lo[5] << 16);
  L.w = (uint)lo[6] | ((uint)lo[7] << 16);
  Wp[((size_t)b*2 + 0)*64 + l] = H;
  Wp[((size_t)b*2 + 1)*64 + l] = L;
}

// ---------------- K5: out[n][c] = sum_k ho[n][k]*Wo[k][c] + bo[c]  via bf16 MFMA, split-Wo.
// ho is already bf16 (exact A operand). Wo = WoHi + WoLo, both passes accumulate into the
// same f32 accumulators -> precision >= previous f32-FMA version.
// 4 waves/block, each wave: 32 rows x 128 cols = 2 row-tiles x 8 col-tiles of 16x16x32.
// Grid = N/128 blocks = 1024 waves = 1 wave/SIMD; launch_bounds(256,1) frees VGPR budget.
__global__ __launch_bounds__(256, 1) void out_mfma(const bf16* __restrict__ ho, const uint4* __restrict__ Wp,
                                                   const float* __restrict__ bo, float* __restrict__ out, int N){
  const int l = threadIdx.x & 63, w = threadIdx.x >> 6;
  const int lr = l & 15, lk = l >> 4;
  const int r0 = blockIdx.x*128 + w*32;
  int ra = r0 + lr;      if (ra > N-1) ra = N-1;
  int rb = r0 + 16 + lr; if (rb > N-1) rb = N-1;
  const bf16* pa = ho + (size_t)ra*1024 + lk*8;   // A frag rt0: row = l&15, k = (l>>4)*8+j
  const bf16* pb = ho + (size_t)rb*1024 + lk*8;   // A frag rt1
  const uint4* pw = Wp + l;

  f32x4 acc[2][8];
  #pragma unroll
  for (int i = 0; i < 2; ++i)
    #pragma unroll
    for (int c = 0; c < 8; ++c)
      #pragma unroll
      for (int j = 0; j < 4; ++j) acc[i][c][j] = 0.f;

  bf16x8 Aa[2], Ab[2], Ba[16], Bb[16];

  auto LD = [&](int ks, bf16x8* A, bf16x8* B){
    A[0] = *(const bf16x8*)(pa + ks*32);
    A[1] = *(const bf16x8*)(pb + ks*32);
    const uint4* q = pw + (size_t)ks*1024;
    #pragma unroll
    for (int u = 0; u < 16; ++u) B[u] = *(const bf16x8*)(q + (size_t)u*64);
  };
  auto MM = [&](bf16x8* A, bf16x8* B){
    #pragma unroll
    for (int c = 0; c < 8; ++c){
      acc[0][c] = __builtin_amdgcn_mfma_f32_16x16x32_bf16(A[0], B[2*c],   acc[0][c], 0, 0, 0);
      acc[1][c] = __builtin_amdgcn_mfma_f32_16x16x32_bf16(A[1], B[2*c],   acc[1][c], 0, 0, 0);
      acc[0][c] = __builtin_amdgcn_mfma_f32_16x16x32_bf16(A[0], B[2*c+1], acc[0][c], 0, 0, 0);
      acc[1][c] = __builtin_amdgcn_mfma_f32_16x16x32_bf16(A[1], B[2*c+1], acc[1][c], 0, 0, 0);
    }
  };

  LD(0, Aa, Ba);
  for (int ks = 0; ks < 32; ks += 2){
    LD(ks + 1, Ab, Bb);           // prefetch odd step
    MM(Aa, Ba);
    if (ks + 2 < 32) LD(ks + 2, Aa, Ba);  // prefetch next even step
    MM(Ab, Bb);
  }

  // Epilogue: D layout col = l&15, row = (l>>4)*4 + reg
  #pragma unroll
  for (int c = 0; c < 8; ++c){
    float bv = bo[c*16 + lr];
    #pragma unroll
    for (int rt = 0; rt < 2; ++rt){
      #pragma unroll
      for (int i = 0; i < 4; ++i){
        int rr = r0 + rt*16 + lk*4 + i;
        if (rr < N) out[(size_t)rr*128 + c*16 + lr] = acc[rt][c][i] + bv;
      }
    }
  }
}

extern "C" void kernel_launch(void* const* d_in, const int* in_sizes, int n_in,
                              void* d_out, int out_size, void* d_ws, size_t ws_size,
                              hipStream_t stream) {
  const float* ast = (const float*)d_in[0];
  const float* Wq  = (const float*)d_in[1];
  const float* bq  = (const float*)d_in[2];
  const float* Wk  = (const float*)d_in[3];
  const float* bk  = (const float*)d_in[4];
  const float* Wo  = (const float*)d_in[5];
  const float* bo  = (const float*)d_in[6];
  const int* ast_key   = (const int*)d_in[7];
  const int* ast_value = (const int*)d_in[8];
  const int* pdg_key   = (const int*)d_in[9];
  const int* pdg_value = (const int*)d_in[10];
  const int E     = in_sizes[7];
  const int n_map = in_sizes[9];
  const int N     = out_size / 128;
  float* out = (float*)d_out;   // reference output dtype is float32

  char* w = (char*)d_ws;
  auto carve = [&](size_t bytes)->char*{
    char* p = w; w += (bytes + 255) & ~size_t(255); return p;
  };
  bf16*  qt      = (bf16*) carve((size_t)N*1024*2);
  float* aq      = (float*)carve((size_t)N*128*4);
  float* Mb      = (float*)carve((size_t)128*1024*4);
  float* cvec    = (float*)carve(1024*4);
  float* uvec    = (float*)carve(1024*4);
  float* sv      = (float*)carve(8*4);
  float* qb      = (float*)carve((size_t)N*8*4);
  int*   counts  = (int*)  carve((size_t)N*4);
  int*   offsets = (int*)  carve((size_t)(N+1)*4);
  int*   cursor  = (int*)  carve((size_t)N*4);
  int*   ridx    = (int*)  carve((size_t)E*4);
  bf16*  ho      = (bf16*) carve((size_t)N*1024*2);
  uint4* Wp      = (uint4*)carve((size_t)256*2*64*16);   // 512 KB packed WoHi/WoLo frags
  (void)ws_size; (void)n_in;

  hipMemsetAsync(aq,     0, (size_t)N*128*4, stream);
  hipMemsetAsync(counts, 0, (size_t)N*4, stream);
  hipMemsetAsync(cursor, 0, (size_t)N*4, stream);

  build_M   <<<64, 256, 0, stream>>>(Wq, Wk, Mb);
  build_bias<<<8, 128, 0, stream>>>(Wq, Wk, bq, bk, cvec, uvec, sv);
  wo_pack   <<<256, 64, 0, stream>>>(Wo, Wp);
  scatter_aq<<<n_map, 64, 0, stream>>>(pdg_key, pdg_value, ast, aq, n_map);
  qt_gemm   <<<(N + 31)/32, 256, 0, stream>>>(aq, Mb, cvec, qt, N);
  qb_kernel <<<N, 64, 0, stream>>>(aq, uvec, sv, qb);
  count_edges<<<(E + 255)/256, 256, 0, stream>>>(ast_value, counts, E);
  scan_offsets<<<1, 1024, 0, stream>>>(counts, offsets, N);
  fill_edges<<<(E + 255)/256, 256, 0, stream>>>(ast_value, ast_key, offsets, cursor, ridx, E);
  seg_attn  <<<(N + 3)/4, 256, 0, stream>>>(qt, qb, offsets, ridx, ast, ho, N);
  out_mfma  <<<(N + 127)/128, 256, 0, stream>>>(ho, Wp, bo, out, N);
}

// Round 2
// 770.789 us; speedup vs baseline: 1.2201x; 1.0648x over previous
//
#include <hip/hip_runtime.h>
#include <hip/hip_bf16.h>
#include <cstdint>

typedef __hip_bfloat16 bf16;
typedef unsigned int uint;
typedef unsigned short ushort;

#define DEVI __device__ __forceinline__

DEVI float blo(uint u){ return __uint_as_float(u << 16); }
DEVI float bhi(uint u){ return __uint_as_float(u & 0xffff0000u); }
// f32 -> bf16 RTNE (finite inputs)
DEVI ushort f2b(float x){ uint u = __float_as_uint(x); uint r = (u + 0x7fffu + ((u >> 16) & 1u)) >> 16; return (ushort)r; }
DEVI uint pack2(float a, float b){ return (uint)f2b(a) | ((uint)f2b(b) << 16); }
DEVI float b2f(ushort h){ return __uint_as_float((uint)h << 16); }

typedef short bf16x8 __attribute__((ext_vector_type(8)));
typedef float f32x4  __attribute__((ext_vector_type(4)));

// 8-lane group sum, pure-VALU DPP butterfly (no LDS pipe, no lgkmcnt):
// xor1 = quad_perm(1,0,3,2)=0xB1, xor2 = quad_perm(2,3,0,1)=0x4E; after those the
// quads are uniform, so row_half_mirror (0x141) delivers the other quad's sum.
DEVI float grp8_sum(float x){
  int y;
  y = __builtin_amdgcn_update_dpp(0, __float_as_int(x), 0xB1, 0xF, 0xF, true);
  x += __int_as_float(y);
  y = __builtin_amdgcn_update_dpp(0, __float_as_int(x), 0x4E, 0xF, 0xF, true);
  x += __int_as_float(y);
  y = __builtin_amdgcn_update_dpp(0, __float_as_int(x), 0x141, 0xF, 0xF, true);
  x += __int_as_float(y);
  return x;
}

// ---------------- K1: M[h][p][m] = sum_j Wq[h][p][j] * Wk[h][m][j], stored Mb[p][h*128+m]
__global__ __launch_bounds__(256) void build_M(const float* __restrict__ Wq, const float* __restrict__ Wk,
                                               float* __restrict__ Mb){
  __shared__ float WkL[128*33];
  __shared__ float WqL[16*33];
  const int t = threadIdx.x;
  const int h = blockIdx.x >> 3, pg = blockIdx.x & 7, p0 = pg*16;
  const float* wk = Wk + (size_t)h*16384;
  const float* wq = Wq + ((size_t)h*128 + p0)*128;
  const int m = t & 127, half = t >> 7;
  float acc[8] = {0,0,0,0,0,0,0,0};
  for (int jc = 0; jc < 4; ++jc){
    __syncthreads();
    #pragma unroll
    for (int i = 0; i < 4; ++i){
      int g = t + 256*i;                 // 1024 float4 groups = 128 x 32
      int mm = g >> 3, j0 = (g & 7)*4;
      float4 v = *(const float4*)(wk + mm*128 + jc*32 + j0);
      float* d = &WkL[mm*33 + j0];
      d[0] = v.x; d[1] = v.y; d[2] = v.z; d[3] = v.w;
    }
    {
      int e = t*2;                       // 512 floats = 16 x 32
      int pr = e >> 5, jj = e & 31;
      float2 v = *(const float2*)(wq + pr*128 + jc*32 + jj);
      WqL[pr*33 + jj] = v.x; WqL[pr*33 + jj + 1] = v.y;
    }
    __syncthreads();
    for (int j = 0; j < 32; ++j){
      float wkv = WkL[m*33 + j];
      #pragma unroll
      for (int r = 0; r < 8; ++r)
        acc[r] = fmaf(WqL[(half*8 + r)*33 + j], wkv, acc[r]);
    }
  }
  #pragma unroll
  for (int r = 0; r < 8; ++r)
    Mb[(size_t)(p0 + half*8 + r)*1024 + h*128 + m] = acc[r];
}

// ---------------- K1b: cvec[h*128+m] = Wk[h][m]·bq[h];  uvec[h*128+p] = Wq[h][p]·bk[h];  sv[h] = bq·bk
__global__ void build_bias(const float* __restrict__ Wq, const float* __restrict__ Wk,
                           const float* __restrict__ bq, const float* __restrict__ bk,
                           float* __restrict__ cvec, float* __restrict__ uvec, float* __restrict__ sv){
  int h = blockIdx.x, m = threadIdx.x;
  const float* wkr = Wk + ((size_t)h*128 + m)*128;
  const float* wqr = Wq + ((size_t)h*128 + m)*128;
  const float* bqr = bq + h*128;
  const float* bkr = bk + h*128;
  float c = 0.f, u = 0.f;
  for (int j = 0; j < 128; ++j){
    c = fmaf(wkr[j], bqr[j], c);
    u = fmaf(wqr[j], bkr[j], u);
  }
  cvec[h*128 + m] = c;
  uvec[h*128 + m] = u;
  if (m == 0){
    float s = 0.f;
    for (int j = 0; j < 128; ++j) s = fmaf(bqr[j], bkr[j], s);
    sv[h] = s;
  }
}

// ---------------- K2: scatter aq[pdg_key[i]] = ast[pdg_value[i]] (f32 + bf16 hi/lo for MFMA)
__global__ void scatter_aq(const int* __restrict__ pk, const int* __restrict__ pv,
                           const float* __restrict__ ast, float* __restrict__ aq,
                           ushort* __restrict__ aqh, ushort* __restrict__ aql, int n_map){
  int i = blockIdx.x;
  if (i >= n_map) return;
  int k = pk[i], src = pv[i];
  int lane = threadIdx.x;
  float2 v = *(const float2*)(ast + (size_t)src*128 + 2*lane);
  *(float2*)(aq + (size_t)k*128 + 2*lane) = v;
  ushort h0 = f2b(v.x), h1 = f2b(v.y);
  ushort l0 = f2b(v.x - b2f(h0)), l1 = f2b(v.y - b2f(h1));
  *(uint*)(aqh + (size_t)k*128 + 2*lane) = (uint)h0 | ((uint)h1 << 16);
  *(uint*)(aql + (size_t)k*128 + 2*lane) = (uint)l0 | ((uint)l1 << 16);
}

// ---------------- generic pack: S[K][C] f32 -> B-fragment-ordered bf16 hi/lo pairs.
// block b = ks*ctn + ct; lane l holds S[k][c] with k = ks*32 + (l>>4)*8 + j, c = ct*16 + (l&15).
// D[(b*2+s)*64 + l], s=0 hi, s=1 lo.
__global__ void frag_pack(const float* __restrict__ S, uint4* __restrict__ D, int C, int ctn){
  const int b = blockIdx.x;
  const int ks = b / ctn, ct = b - ks*ctn;
  const int l = threadIdx.x;           // 64
  const int kb = ks*32 + (l >> 4)*8;
  const int c  = ct*16 + (l & 15);
  ushort hi[8], lo[8];
  #pragma unroll
  for (int j = 0; j < 8; ++j){
    float wv = S[(size_t)(kb + j)*C + c];
    ushort hh = f2b(wv);
    hi[j] = hh;
    lo[j] = f2b(wv - b2f(hh));
  }
  uint4 H, L;
  H.x = (uint)hi[0] | ((uint)hi[1] << 16);
  H.y = (uint)hi[2] | ((uint)hi[3] << 16);
  H.z = (uint)hi[4] | ((uint)hi[5] << 16);
  H.w = (uint)hi[6] | ((uint)hi[7] << 16);
  L.x = (uint)lo[0] | ((uint)lo[1] << 16);
  L.y = (uint)lo[2] | ((uint)lo[3] << 16);
  L.z = (uint)lo[4] | ((uint)lo[5] << 16);
  L.w = (uint)lo[6] | ((uint)lo[7] << 16);
  D[((size_t)b*2 + 0)*64 + l] = H;
  D[((size_t)b*2 + 1)*64 + l] = L;
}

// ---------------- K3: qt[n][c] = sum_p aq[n][p]*Mb[p][c] + cvec[c]  via split-bf16 MFMA (3 passes).
// A = aq hi/lo (from scatter_aq), B = Mb hi/lo (frag_pack, ctn=64). Block = 16 rows, wave w = cols w*256..+256.
__global__ __launch_bounds__(256, 1) void qt_mfma(const ushort* __restrict__ aqh, const ushort* __restrict__ aql,
                                                  const uint4* __restrict__ Mp, const float* __restrict__ cvec,
                                                  bf16* __restrict__ qt, int N){
  const int l = threadIdx.x & 63, w = threadIdx.x >> 6;
  const int lr = l & 15, lk = l >> 4;
  const int r0 = blockIdx.x*16;
  int ra = r0 + lr; if (ra > N-1) ra = N-1;
  const ushort* ph = aqh + (size_t)ra*128 + lk*8;
  const ushort* pl = aql + (size_t)ra*128 + lk*8;
  bf16x8 Ah[4], Al[4];
  #pragma unroll
  for (int ks = 0; ks < 4; ++ks){
    Ah[ks] = *(const bf16x8*)(ph + ks*32);
    Al[ks] = *(const bf16x8*)(pl + ks*32);
  }
  const int ct0 = w*16;
  for (int ct = 0; ct < 16; ++ct){
    const int ctg = ct0 + ct;
    f32x4 acc = {0.f, 0.f, 0.f, 0.f};
    #pragma unroll
    for (int ks = 0; ks < 4; ++ks){
      const uint4* q = Mp + ((size_t)(ks*64 + ctg)*2)*64 + l;
      bf16x8 Bh = *(const bf16x8*)q;
      bf16x8 Bl = *(const bf16x8*)(q + 64);
      acc = __builtin_amdgcn_mfma_f32_16x16x32_bf16(Ah[ks], Bh, acc, 0, 0, 0);
      acc = __builtin_amdgcn_mfma_f32_16x16x32_bf16(Al[ks], Bh, acc, 0, 0, 0);
      acc = __builtin_amdgcn_mfma_f32_16x16x32_bf16(Ah[ks], Bl, acc, 0, 0, 0);
    }
    const int cc = ctg*16 + lr;
    const float bv = cvec[cc];
    #pragma unroll
    for (int i = 0; i < 4; ++i){
      int rr = r0 + lk*4 + i;
      if (rr < N) ((ushort*)qt)[(size_t)rr*1024 + cc] = f2b(acc[i] + bv);
    }
  }
}

// ---------------- K3b: qb[n][h] = aq[n]·uvec[h] + sv[h]
__global__ void qb_kernel(const float* __restrict__ aq, const float* __restrict__ uvec,
                          const float* __restrict__ sv, float* __restrict__ qb){
  int n = blockIdx.x, lane = threadIdx.x;
  int h = lane >> 3, g = lane & 7;
  const float* ar = aq + (size_t)n*128 + g*16;
  const float* ur = uvec + h*128 + g*16;
  float dot = 0.f;
  #pragma unroll
  for (int k = 0; k < 16; ++k) dot = fmaf(ar[k], ur[k], dot);
  dot += __shfl_xor(dot, 1);
  dot += __shfl_xor(dot, 2);
  dot += __shfl_xor(dot, 4);
  if (g == 0) qb[(size_t)n*8 + h] = dot + sv[h];
}

// ---------------- K4: CSR build
__global__ void count_edges(const int* __restrict__ av, int* __restrict__ counts, int E){
  int e = blockIdx.x*256 + threadIdx.x;
  if (e < E) atomicAdd(&counts[av[e]], 1);
}

__global__ void scan_offsets(const int* __restrict__ counts, int* __restrict__ offsets, int N){
  __shared__ int pa[1024];
  __shared__ int pb[1024];
  int t = threadIdx.x;
  int CH = (N + 1023) >> 10;
  int b = t*CH, e = b + CH;
  if (b > N) b = N;
  if (e > N) e = N;
  int s = 0;
  for (int i = b; i < e; ++i) s += counts[i];
  pa[t] = s;
  __syncthreads();
  int* src = pa; int* dst = pb;
  for (int off = 1; off < 1024; off <<= 1){
    int v = src[t];
    if (t >= off) v += src[t - off];
    __syncthreads();
    dst[t] = v;
    __syncthreads();
    int* tmp = src; src = dst; dst = tmp;
  }
  int run = src[t] - s;
  for (int i = b; i < e; ++i){ offsets[i] = run; run += counts[i]; }
  if (t == 1023) offsets[N] = src[1023];
}

__global__ void fill_edges(const int* __restrict__ av, const int* __restrict__ akey,
                           const int* __restrict__ offsets, int* __restrict__ cursor,
                           int* __restrict__ ridx, int E){
  int e = blockIdx.x*256 + threadIdx.x;
  if (e < E){
    int seg = av[e];
    int pos = offsets[seg] + atomicAdd(&cursor[seg], 1);
    ridx[pos] = akey[e];
  }
}

// ---------------- K6: per-segment attention. 1 wave = 1 segment.
// v2: 2-edge ILP + 2-pair-deep prefetch (SSA renaming, no movs) + pure-DPP 8-lane reduce
// (no LDS pipe in the chain) + scalarized ridx loads (readfirstlane'd beg/end -> s_load).
__global__ __launch_bounds__(256) void seg_attn(
    const bf16* __restrict__ qt, const float* __restrict__ qb,
    const int* __restrict__ offsets, const int* __restrict__ ridx,
    const float* __restrict__ ast, bf16* __restrict__ ho, int N)
{
  const int wid  = threadIdx.x >> 6;
  const int lane = threadIdx.x & 63;
  const int n = blockIdx.x*4 + wid;
  if (n >= N) return;
  const int beg = __builtin_amdgcn_readfirstlane(offsets[n]);
  const int end = __builtin_amdgcn_readfirstlane(offsets[n+1]);
  const int deg = end - beg;
  const int h = lane >> 3, g = lane & 7;

  const uint4* qp = (const uint4*)(qt + (size_t)n*1024 + h*128 + g*16);
  const uint4 qa = qp[0], qc = qp[1];
  const float4 q0 = make_float4(blo(qa.x), bhi(qa.x), blo(qa.y), bhi(qa.y));
  const float4 q1 = make_float4(blo(qa.z), bhi(qa.z), blo(qa.w), bhi(qa.w));
  const float4 q2 = make_float4(blo(qc.x), bhi(qc.x), blo(qc.y), bhi(qc.y));
  const float4 q3 = make_float4(blo(qc.z), bhi(qc.z), blo(qc.w), bhi(qc.w));
  const float qbv = qb[(size_t)n*8 + h];
  const float isd = 0.08838834764831845f;  // 1/sqrt(128)

  const int* rp = ridx + beg;

  float den = 0.f;
  float4 x0 = make_float4(0,0,0,0), x1 = x0, x2 = x0, x3 = x0;

  if (deg > 0){
    #define ROWP(ee) ((const float4*)(ast + (size_t)rp[(ee) < deg ? (ee) : deg-1]*128) + g*4)
    float4 A0, A1, A2, A3, B0, B1, B2, B3;
    { const float4* p = ROWP(0); A0 = p[0]; A1 = p[1]; A2 = p[2]; A3 = p[3]; }
    { const float4* p = ROWP(1); B0 = p[0]; B1 = p[1]; B2 = p[2]; B3 = p[3]; }
    int e = 0;
    for (; e + 1 < deg; e += 2){
      // consume-by-rename, then immediately issue the next pair's loads
      const float4 a0 = A0, a1 = A1, a2 = A2, a3 = A3;
      const float4 b0 = B0, b1 = B1, b2 = B2, b3 = B3;
      { const float4* p = ROWP(e + 2); A0 = p[0]; A1 = p[1]; A2 = p[2]; A3 = p[3]; }
      { const float4* p = ROWP(e + 3); B0 = p[0]; B1 = p[1]; B2 = p[2]; B3 = p[3]; }

      float dA = 0.f, dB = 0.f;
      dA = fmaf(a0.x, q0.x, dA); dA = fmaf(a0.y, q0.y, dA);
      dA = fmaf(a0.z, q0.z, dA); dA = fmaf(a0.w, q0.w, dA);
      dA = fmaf(a1.x, q1.x, dA); dA = fmaf(a1.y, q1.y, dA);
      dA = fmaf(a1.z, q1.z, dA); dA = fmaf(a1.w, q1.w, dA);
      dA = fmaf(a2.x, q2.x, dA); dA = fmaf(a2.y, q2.y, dA);
      dA = fmaf(a2.z, q2.z, dA); dA = fmaf(a2.w, q2.w, dA);
      dA = fmaf(a3.x, q3.x, dA); dA = fmaf(a3.y, q3.y, dA);
      dA = fmaf(a3.z, q3.z, dA); dA = fmaf(a3.w, q3.w, dA);
      dB = fmaf(b0.x, q0.x, dB); dB = fmaf(b0.y, q0.y, dB);
      dB = fmaf(b0.z, q0.z, dB); dB = fmaf(b0.w, q0.w, dB);
      dB = fmaf(b1.x, q1.x, dB); dB = fmaf(b1.y, q1.y, dB);
      dB = fmaf(b1.z, q1.z, dB); dB = fmaf(b1.w, q1.w, dB);
      dB = fmaf(b2.x, q2.x, dB); dB = fmaf(b2.y, q2.y, dB);
      dB = fmaf(b2.z, q2.z, dB); dB = fmaf(b2.w, q2.w, dB);
      dB = fmaf(b3.x, q3.x, dB); dB = fmaf(b3.y, q3.y, dB);
      dB = fmaf(b3.z, q3.z, dB); dB = fmaf(b3.w, q3.w, dB);
      dA = grp8_sum(dA);
      dB = grp8_sum(dB);

      const float pA = __expf((dA + qbv) * isd);
      const float pB = __expf((dB + qbv) * isd);
      den += pA; den += pB;

      x0.x = fmaf(pA, a0.x, x0.x); x0.y = fmaf(pA, a0.y, x0.y);
      x0.z = fmaf(pA, a0.z, x0.z); x0.w = fmaf(pA, a0.w, x0.w);
      x1.x = fmaf(pA, a1.x, x1.x); x1.y = fmaf(pA, a1.y, x1.y);
      x1.z = fmaf(pA, a1.z, x1.z); x1.w = fmaf(pA, a1.w, x1.w);
      x2.x = fmaf(pA, a2.x, x2.x); x2.y = fmaf(pA, a2.y, x2.y);
      x2.z = fmaf(pA, a2.z, x2.z); x2.w = fmaf(pA, a2.w, x2.w);
      x3.x = fmaf(pA, a3.x, x3.x); x3.y = fmaf(pA, a3.y, x3.y);
      x3.z = fmaf(pA, a3.z, x3.z); x3.w = fmaf(pA, a3.w, x3.w);
      x0.x = fmaf(pB, b0.x, x0.x); x0.y = fmaf(pB, b0.y, x0.y);
      x0.z = fmaf(pB, b0.z, x0.z); x0.w = fmaf(pB, b0.w, x0.w);
      x1.x = fmaf(pB, b1.x, x1.x); x1.y = fmaf(pB, b1.y, x1.y);
      x1.z = fmaf(pB, b1.z, x1.z); x1.w = fmaf(pB, b1.w, x1.w);
      x2.x = fmaf(pB, b2.x, x2.x); x2.y = fmaf(pB, b2.y, x2.y);
      x2.z = fmaf(pB, b2.z, x2.z); x2.w = fmaf(pB, b2.w, x2.w);
      x3.x = fmaf(pB, b3.x, x3.x); x3.y = fmaf(pB, b3.y, x3.y);
      x3.z = fmaf(pB, b3.z, x3.z); x3.w = fmaf(pB, b3.w, x3.w);
    }
    if (e < deg){
      const float4 a0 = A0, a1 = A1, a2 = A2, a3 = A3;
      float dA = 0.f;
      dA = fmaf(a0.x, q0.x, dA); dA = fmaf(a0.y, q0.y, dA);
      dA = fmaf(a0.z, q0.z, dA); dA = fmaf(a0.w, q0.w, dA);
      dA = fmaf(a1.x, q1.x, dA); dA = fmaf(a1.y, q1.y, dA);
      dA = fmaf(a1.z, q1.z, dA); dA = fmaf(a1.w, q1.w, dA);
      dA = fmaf(a2.x, q2.x, dA); dA = fmaf(a2.y, q2.y, dA);
      dA = fmaf(a2.z, q2.z, dA); dA = fmaf(a2.w, q2.w, dA);
      dA = fmaf(a3.x, q3.x, dA); dA = fmaf(a3.y, q3.y, dA);
      dA = fmaf(a3.z, q3.z, dA); dA = fmaf(a3.w, q3.w, dA);
      dA = grp8_sum(dA);
      const float pA = __expf((dA + qbv) * isd);
      den += pA;
      x0.x = fmaf(pA, a0.x, x0.x); x0.y = fmaf(pA, a0.y, x0.y);
      x0.z = fmaf(pA, a0.z, x0.z); x0.w = fmaf(pA, a0.w, x0.w);
      x1.x = fmaf(pA, a1.x, x1.x); x1.y = fmaf(pA, a1.y, x1.y);
      x1.z = fmaf(pA, a1.z, x1.z); x1.w = fmaf(pA, a1.w, x1.w);
      x2.x = fmaf(pA, a2.x, x2.x); x2.y = fmaf(pA, a2.y, x2.y);
      x2.z = fmaf(pA, a2.z, x2.z); x2.w = fmaf(pA, a2.w, x2.w);
      x3.x = fmaf(pA, a3.x, x3.x); x3.y = fmaf(pA, a3.y, x3.y);
      x3.z = fmaf(pA, a3.z, x3.z); x3.w = fmaf(pA, a3.w, x3.w);
    }
    #undef ROWP
  }
  const float r = (deg > 0) ? (1.f / den) : 0.f;

  uint4 o0, o1;
  o0.x = pack2(x0.x*r, x0.y*r); o0.y = pack2(x0.z*r, x0.w*r);
  o0.z = pack2(x1.x*r, x1.y*r); o0.w = pack2(x1.z*r, x1.w*r);
  o1.x = pack2(x2.x*r, x2.y*r); o1.y = pack2(x2.z*r, x2.w*r);
  o1.z = pack2(x3.x*r, x3.y*r); o1.w = pack2(x3.z*r, x3.w*r);
  uint4* hb = (uint4*)(ho + (size_t)n*1024 + h*128 + g*16);
  hb[0] = o0;
  hb[1] = o1;
}

// ---------------- K5: out[n][c] = sum_k ho[n][k]*Wo[k][c] + bo[c]  via bf16 MFMA, split-Wo.
__global__ __launch_bounds__(256, 1) void out_mfma(const bf16* __restrict__ ho, const uint4* __restrict__ Wp,
                                                   const float* __restrict__ bo, float* __restrict__ out, int N){
  const int l = threadIdx.x & 63, w = threadIdx.x >> 6;
  const int lr = l & 15, lk = l >> 4;
  const int r0 = blockIdx.x*128 + w*32;
  int ra = r0 + lr;      if (ra > N-1) ra = N-1;
  int rb = r0 + 16 + lr; if (rb > N-1) rb = N-1;
  const bf16* pa = ho + (size_t)ra*1024 + lk*8;
  const bf16* pb = ho + (size_t)rb*1024 + lk*8;
  const uint4* pw = Wp + l;

  f32x4 acc[2][8];
  #pragma unroll
  for (int i = 0; i < 2; ++i)
    #pragma unroll
    for (int c = 0; c < 8; ++c)
      #pragma unroll
      for (int j = 0; j < 4; ++j) acc[i][c][j] = 0.f;

  bf16x8 Aa[2], Ab[2], Ba[16], Bb[16];

  auto LD = [&](int ks, bf16x8* A, bf16x8* B){
    A[0] = *(const bf16x8*)(pa + ks*32);
    A[1] = *(const bf16x8*)(pb + ks*32);
    const uint4* q = pw + (size_t)ks*1024;
    #pragma unroll
    for (int u = 0; u < 16; ++u) B[u] = *(const bf16x8*)(q + (size_t)u*64);
  };
  auto MM = [&](bf16x8* A, bf16x8* B){
    #pragma unroll
    for (int c = 0; c < 8; ++c){
      acc[0][c] = __builtin_amdgcn_mfma_f32_16x16x32_bf16(A[0], B[2*c],   acc[0][c], 0, 0, 0);
      acc[1][c] = __builtin_amdgcn_mfma_f32_16x16x32_bf16(A[1], B[2*c],   acc[1][c], 0, 0, 0);
      acc[0][c] = __builtin_amdgcn_mfma_f32_16x16x32_bf16(A[0], B[2*c+1], acc[0][c], 0, 0, 0);
      acc[1][c] = __builtin_amdgcn_mfma_f32_16x16x32_bf16(A[1], B[2*c+1], acc[1][c], 0, 0, 0);
    }
  };

  LD(0, Aa, Ba);
  for (int ks = 0; ks < 32; ks += 2){
    LD(ks + 1, Ab, Bb);
    MM(Aa, Ba);
    if (ks + 2 < 32) LD(ks + 2, Aa, Ba);
    MM(Ab, Bb);
  }

  #pragma unroll
  for (int c = 0; c < 8; ++c){
    float bv = bo[c*16 + lr];
    #pragma unroll
    for (int rt = 0; rt < 2; ++rt){
      #pragma unroll
      for (int i = 0; i < 4; ++i){
        int rr = r0 + rt*16 + lk*4 + i;
        if (rr < N) out[(size_t)rr*128 + c*16 + lr] = acc[rt][c][i] + bv;
      }
    }
  }
}

extern "C" void kernel_launch(void* const* d_in, const int* in_sizes, int n_in,
                              void* d_out, int out_size, void* d_ws, size_t ws_size,
                              hipStream_t stream) {
  const float* ast = (const float*)d_in[0];
  const float* Wq  = (const float*)d_in[1];
  const float* bq  = (const float*)d_in[2];
  const float* Wk  = (const float*)d_in[3];
  const float* bk  = (const float*)d_in[4];
  const float* Wo  = (const float*)d_in[5];
  const float* bo  = (const float*)d_in[6];
  const int* ast_key   = (const int*)d_in[7];
  const int* ast_value = (const int*)d_in[8];
  const int* pdg_key   = (const int*)d_in[9];
  const int* pdg_value = (const int*)d_in[10];
  const int E     = in_sizes[7];
  const int n_map = in_sizes[9];
  const int N     = out_size / 128;
  float* out = (float*)d_out;   // reference output dtype is float32

  char* w = (char*)d_ws;
  auto carve = [&](size_t bytes)->char*{
    char* p = w; w += (bytes + 255) & ~size_t(255); return p;
  };
  bf16*  qt      = (bf16*) carve((size_t)N*1024*2);
  float* aq      = (float*)carve((size_t)N*128*4);
  float* Mb      = (float*)carve((size_t)128*1024*4);
  float* cvec    = (float*)carve(1024*4);
  float* uvec    = (float*)carve(1024*4);
  float* sv      = (float*)carve(8*4);
  float* qb      = (float*)carve((size_t)N*8*4);
  int*   counts  = (int*)  carve((size_t)N*4);
  int*   offsets = (int*)  carve((size_t)(N+1)*4);
  int*   cursor  = (int*)  carve((size_t)N*4);
  int*   ridx    = (int*)  carve((size_t)E*4);
  bf16*  ho      = (bf16*) carve((size_t)N*1024*2);
  uint4* Wp      = (uint4*)carve((size_t)256*2*64*16);   // 512 KB packed WoHi/WoLo frags
  ushort* aqh    = (ushort*)carve((size_t)N*128*2);
  ushort* aql    = (ushort*)carve((size_t)N*128*2);
  uint4* Mp      = (uint4*)carve((size_t)256*2*64*16);   // 512 KB packed MbHi/MbLo frags
  (void)ws_size; (void)n_in;

  hipMemsetAsync(aq,     0, (size_t)N*128*4, stream);
  hipMemsetAsync(aqh,    0, (size_t)N*128*2, stream);
  hipMemsetAsync(aql,    0, (size_t)N*128*2, stream);
  hipMemsetAsync(counts, 0, (size_t)N*4, stream);
  hipMemsetAsync(cursor, 0, (size_t)N*4, stream);

  build_M   <<<64, 256, 0, stream>>>(Wq, Wk, Mb);
  build_bias<<<8, 128, 0, stream>>>(Wq, Wk, bq, bk, cvec, uvec, sv);
  frag_pack <<<256, 64, 0, stream>>>(Wo, Wp, 128, 8);    // K=1024, C=128
  scatter_aq<<<n_map, 64, 0, stream>>>(pdg_key, pdg_value, ast, aq, aqh, aql, n_map);
  frag_pack <<<256, 64, 0, stream>>>(Mb, Mp, 1024, 64);  // K=128,  C=1024
  qt_mfma   <<<(N + 15)/16, 256, 0, stream>>>(aqh, aql, Mp, cvec, qt, N);
  qb_kernel <<<N, 64, 0, stream>>>(aq, uvec, sv, qb);
  count_edges<<<(E + 255)/256, 256, 0, stream>>>(ast_value, counts, E);
  scan_offsets<<<1, 1024, 0, stream>>>(counts, offsets, N);
  fill_edges<<<(E + 255)/256, 256, 0, stream>>>(ast_value, ast_key, offsets, cursor, ridx, E);
  seg_attn  <<<(N + 3)/4, 256, 0, stream>>>(qt, qb, offsets, ridx, ast, ho, N);
  out_mfma  <<<(N + 127)/128, 256, 0, stream>>>(ho, Wp, bo, out, N);
}

// Round 3
// 756.677 us; speedup vs baseline: 1.2429x; 1.0186x over previous
//
#include <hip/hip_runtime.h>
#include <hip/hip_bf16.h>
#include <cstdint>

typedef __hip_bfloat16 bf16;
typedef unsigned int uint;
typedef unsigned short ushort;

#define DEVI __device__ __forceinline__

DEVI float blo(uint u){ return __uint_as_float(u << 16); }
DEVI float bhi(uint u){ return __uint_as_float(u & 0xffff0000u); }
// f32 -> bf16 RTNE (finite inputs)
DEVI ushort f2b(float x){ uint u = __float_as_uint(x); uint r = (u + 0x7fffu + ((u >> 16) & 1u)) >> 16; return (ushort)r; }
DEVI uint pack2(float a, float b){ return (uint)f2b(a) | ((uint)f2b(b) << 16); }
DEVI float b2f(ushort h){ return __uint_as_float((uint)h << 16); }

typedef short bf16x8 __attribute__((ext_vector_type(8)));
typedef float f32x4  __attribute__((ext_vector_type(4)));

// 16-lane row sum via DPP row_ror 1/2/4/8 (rotation-compose reduction, pure VALU).
DEVI float row16_sum(float x){
  int y;
  y = __builtin_amdgcn_update_dpp(0, __float_as_int(x), 0x121, 0xF, 0xF, true); x += __int_as_float(y);
  y = __builtin_amdgcn_update_dpp(0, __float_as_int(x), 0x122, 0xF, 0xF, true); x += __int_as_float(y);
  y = __builtin_amdgcn_update_dpp(0, __float_as_int(x), 0x124, 0xF, 0xF, true); x += __int_as_float(y);
  y = __builtin_amdgcn_update_dpp(0, __float_as_int(x), 0x128, 0xF, 0xF, true); x += __int_as_float(y);
  return x;
}

// ---------------- K1: M[h][p][m] = sum_j Wq[h][p][j] * Wk[h][m][j], stored Mb[p][h*128+m]
__global__ __launch_bounds__(256) void build_M(const float* __restrict__ Wq, const float* __restrict__ Wk,
                                               float* __restrict__ Mb){
  __shared__ float WkL[128*33];
  __shared__ float WqL[16*33];
  const int t = threadIdx.x;
  const int h = blockIdx.x >> 3, pg = blockIdx.x & 7, p0 = pg*16;
  const float* wk = Wk + (size_t)h*16384;
  const float* wq = Wq + ((size_t)h*128 + p0)*128;
  const int m = t & 127, half = t >> 7;
  float acc[8] = {0,0,0,0,0,0,0,0};
  for (int jc = 0; jc < 4; ++jc){
    __syncthreads();
    #pragma unroll
    for (int i = 0; i < 4; ++i){
      int g = t + 256*i;                 // 1024 float4 groups = 128 x 32
      int mm = g >> 3, j0 = (g & 7)*4;
      float4 v = *(const float4*)(wk + mm*128 + jc*32 + j0);
      float* d = &WkL[mm*33 + j0];
      d[0] = v.x; d[1] = v.y; d[2] = v.z; d[3] = v.w;
    }
    {
      int e = t*2;                       // 512 floats = 16 x 32
      int pr = e >> 5, jj = e & 31;
      float2 v = *(const float2*)(wq + pr*128 + jc*32 + jj);
      WqL[pr*33 + jj] = v.x; WqL[pr*33 + jj + 1] = v.y;
    }
    __syncthreads();
    for (int j = 0; j < 32; ++j){
      float wkv = WkL[m*33 + j];
      #pragma unroll
      for (int r = 0; r < 8; ++r)
        acc[r] = fmaf(WqL[(half*8 + r)*33 + j], wkv, acc[r]);
    }
  }
  #pragma unroll
  for (int r = 0; r < 8; ++r)
    Mb[(size_t)(p0 + half*8 + r)*1024 + h*128 + m] = acc[r];
}

// ---------------- K1b
__global__ void build_bias(const float* __restrict__ Wq, const float* __restrict__ Wk,
                           const float* __restrict__ bq, const float* __restrict__ bk,
                           float* __restrict__ cvec, float* __restrict__ uvec, float* __restrict__ sv){
  int h = blockIdx.x, m = threadIdx.x;
  const float* wkr = Wk + ((size_t)h*128 + m)*128;
  const float* wqr = Wq + ((size_t)h*128 + m)*128;
  const float* bqr = bq + h*128;
  const float* bkr = bk + h*128;
  float c = 0.f, u = 0.f;
  for (int j = 0; j < 128; ++j){
    c = fmaf(wkr[j], bqr[j], c);
    u = fmaf(wqr[j], bkr[j], u);
  }
  cvec[h*128 + m] = c;
  uvec[h*128 + m] = u;
  if (m == 0){
    float s = 0.f;
    for (int j = 0; j < 128; ++j) s = fmaf(bqr[j], bkr[j], s);
    sv[h] = s;
  }
}

// ---------------- K2: scatter aq[pdg_key[i]] = ast[pdg_value[i]] (f32 + bf16 hi/lo for MFMA)
__global__ void scatter_aq(const int* __restrict__ pk, const int* __restrict__ pv,
                           const float* __restrict__ ast, float* __restrict__ aq,
                           ushort* __restrict__ aqh, ushort* __restrict__ aql, int n_map){
  int i = blockIdx.x;
  if (i >= n_map) return;
  int k = pk[i], src = pv[i];
  int lane = threadIdx.x;
  float2 v = *(const float2*)(ast + (size_t)src*128 + 2*lane);
  *(float2*)(aq + (size_t)k*128 + 2*lane) = v;
  ushort h0 = f2b(v.x), h1 = f2b(v.y);
  ushort l0 = f2b(v.x - b2f(h0)), l1 = f2b(v.y - b2f(h1));
  *(uint*)(aqh + (size_t)k*128 + 2*lane) = (uint)h0 | ((uint)h1 << 16);
  *(uint*)(aql + (size_t)k*128 + 2*lane) = (uint)l0 | ((uint)l1 << 16);
}

// ---------------- generic pack: S[K][C] f32 -> B-fragment-ordered bf16 hi/lo pairs.
__global__ void frag_pack(const float* __restrict__ S, uint4* __restrict__ D, int C, int ctn){
  const int b = blockIdx.x;
  const int ks = b / ctn, ct = b - ks*ctn;
  const int l = threadIdx.x;           // 64
  const int kb = ks*32 + (l >> 4)*8;
  const int c  = ct*16 + (l & 15);
  ushort hi[8], lo[8];
  #pragma unroll
  for (int j = 0; j < 8; ++j){
    float wv = S[(size_t)(kb + j)*C + c];
    ushort hh = f2b(wv);
    hi[j] = hh;
    lo[j] = f2b(wv - b2f(hh));
  }
  uint4 H, L;
  H.x = (uint)hi[0] | ((uint)hi[1] << 16);
  H.y = (uint)hi[2] | ((uint)hi[3] << 16);
  H.z = (uint)hi[4] | ((uint)hi[5] << 16);
  H.w = (uint)hi[6] | ((uint)hi[7] << 16);
  L.x = (uint)lo[0] | ((uint)lo[1] << 16);
  L.y = (uint)lo[2] | ((uint)lo[3] << 16);
  L.z = (uint)lo[4] | ((uint)lo[5] << 16);
  L.w = (uint)lo[6] | ((uint)lo[7] << 16);
  D[((size_t)b*2 + 0)*64 + l] = H;
  D[((size_t)b*2 + 1)*64 + l] = L;
}

// ---------------- K3: qt = aq*Mb + cvec via split-bf16 MFMA, out_mfma-style structure.
// 256-ish blocks of 128 rows; wave = 32 rows (2 row-tiles); A frags in regs (hi+lo, 4 ks);
// stream 64 col-tiles with double-buffered B (4 ks x hi/lo). 24 MFMA per col-tile.
__global__ __launch_bounds__(256, 1) void qt_mfma(const ushort* __restrict__ aqh, const ushort* __restrict__ aql,
                                                  const uint4* __restrict__ Mp, const float* __restrict__ cvec,
                                                  bf16* __restrict__ qt, int N){
  const int l = threadIdx.x & 63, w = threadIdx.x >> 6;
  const int lr = l & 15, lk = l >> 4;
  const int r0 = blockIdx.x*128 + w*32;
  int ra = r0 + lr;      if (ra > N-1) ra = N-1;
  int rb = r0 + 16 + lr; if (rb > N-1) rb = N-1;

  bf16x8 Ah0[4], Al0[4], Ah1[4], Al1[4];
  #pragma unroll
  for (int ks = 0; ks < 4; ++ks){
    Ah0[ks] = *(const bf16x8*)(aqh + (size_t)ra*128 + lk*8 + ks*32);
    Al0[ks] = *(const bf16x8*)(aql + (size_t)ra*128 + lk*8 + ks*32);
    Ah1[ks] = *(const bf16x8*)(aqh + (size_t)rb*128 + lk*8 + ks*32);
    Al1[ks] = *(const bf16x8*)(aql + (size_t)rb*128 + lk*8 + ks*32);
  }
  const uint4* pw = Mp + l;

  bf16x8 Ba[8], Bb[8];   // [ks*2 + {hi,lo}]
  auto LDB = [&](int ct, bf16x8* B){
    #pragma unroll
    for (int ks = 0; ks < 4; ++ks){
      const uint4* q = pw + ((size_t)(ks*64 + ct)*2)*64;
      B[ks*2]   = *(const bf16x8*)q;
      B[ks*2+1] = *(const bf16x8*)(q + 64);
    }
  };
  auto DO = [&](int ct, bf16x8* B){
    f32x4 a0 = {0.f,0.f,0.f,0.f}, a1 = {0.f,0.f,0.f,0.f};
    #pragma unroll
    for (int ks = 0; ks < 4; ++ks){
      a0 = __builtin_amdgcn_mfma_f32_16x16x32_bf16(Ah0[ks], B[2*ks],   a0, 0, 0, 0);
      a1 = __builtin_amdgcn_mfma_f32_16x16x32_bf16(Ah1[ks], B[2*ks],   a1, 0, 0, 0);
      a0 = __builtin_amdgcn_mfma_f32_16x16x32_bf16(Al0[ks], B[2*ks],   a0, 0, 0, 0);
      a1 = __builtin_amdgcn_mfma_f32_16x16x32_bf16(Al1[ks], B[2*ks],   a1, 0, 0, 0);
      a0 = __builtin_amdgcn_mfma_f32_16x16x32_bf16(Ah0[ks], B[2*ks+1], a0, 0, 0, 0);
      a1 = __builtin_amdgcn_mfma_f32_16x16x32_bf16(Ah1[ks], B[2*ks+1], a1, 0, 0, 0);
    }
    const int cc = ct*16 + lr;
    const float bv = cvec[cc];
    #pragma unroll
    for (int i = 0; i < 4; ++i){
      int rr0 = r0 + lk*4 + i;
      if (rr0 < N) ((ushort*)qt)[(size_t)rr0*1024 + cc] = f2b(a0[i] + bv);
      int rr1 = r0 + 16 + lk*4 + i;
      if (rr1 < N) ((ushort*)qt)[(size_t)rr1*1024 + cc] = f2b(a1[i] + bv);
    }
  };

  LDB(0, Ba);
  for (int ct = 0; ct < 64; ct += 2){
    LDB(ct + 1, Bb);
    DO(ct, Ba);
    if (ct + 2 < 64) LDB(ct + 2, Ba);
    DO(ct + 1, Bb);
  }
}

// ---------------- K3b: qb[n][h] = aq[n]·uvec[h] + sv[h]
__global__ void qb_kernel(const float* __restrict__ aq, const float* __restrict__ uvec,
                          const float* __restrict__ sv, float* __restrict__ qb){
  int n = blockIdx.x, lane = threadIdx.x;
  int h = lane >> 3, g = lane & 7;
  const float* ar = aq + (size_t)n*128 + g*16;
  const float* ur = uvec + h*128 + g*16;
  float dot = 0.f;
  #pragma unroll
  for (int k = 0; k < 16; ++k) dot = fmaf(ar[k], ur[k], dot);
  dot += __shfl_xor(dot, 1);
  dot += __shfl_xor(dot, 2);
  dot += __shfl_xor(dot, 4);
  if (g == 0) qb[(size_t)n*8 + h] = dot + sv[h];
}

// ---------------- K4: CSR build
__global__ void count_edges(const int* __restrict__ av, int* __restrict__ counts, int E){
  int e = blockIdx.x*256 + threadIdx.x;
  if (e < E) atomicAdd(&counts[av[e]], 1);
}

__global__ void scan_offsets(const int* __restrict__ counts, int* __restrict__ offsets, int N){
  __shared__ int pa[1024];
  __shared__ int pb[1024];
  int t = threadIdx.x;
  int CH = (N + 1023) >> 10;
  int b = t*CH, e = b + CH;
  if (b > N) b = N;
  if (e > N) e = N;
  int s = 0;
  for (int i = b; i < e; ++i) s += counts[i];
  pa[t] = s;
  __syncthreads();
  int* src = pa; int* dst = pb;
  for (int off = 1; off < 1024; off <<= 1){
    int v = src[t];
    if (t >= off) v += src[t - off];
    __syncthreads();
    dst[t] = v;
    __syncthreads();
    int* tmp = src; src = dst; dst = tmp;
  }
  int run = src[t] - s;
  for (int i = b; i < e; ++i){ offsets[i] = run; run += counts[i]; }
  if (t == 1023) offsets[N] = src[1023];
}

__global__ void fill_edges(const int* __restrict__ av, const int* __restrict__ akey,
                           const int* __restrict__ offsets, int* __restrict__ cursor,
                           int* __restrict__ ridx, int E){
  int e = blockIdx.x*256 + threadIdx.x;
  if (e < E){
    int seg = av[e];
    int pos = offsets[seg] + atomicAdd(&cursor[seg], 1);
    ridx[pos] = akey[e];
  }
}

// ---------------- K6: per-segment attention v3. 1 wave = 1 segment.
// Lane layout: grp = lane>>4 (4 groups of 16), d4 = lane&15; group grp owns heads
// {2grp, 2grp+1}; lane covers dims d4*8 .. d4*8+7 (32B = 2 float4 loads/edge).
// Row duplication 4x (was 8x), 2 VMEM instrs/edge (was 4). Score reduce = DPP row_ror
// tree over the 16-lane group, both heads. 6 edges in flight (3 pair-buffers, period-3).
__global__ __launch_bounds__(256) void seg_attn(
    const bf16* __restrict__ qt, const float* __restrict__ qb,
    const int* __restrict__ offsets, const int* __restrict__ ridx,
    const float* __restrict__ ast, bf16* __restrict__ ho, int N)
{
  const int wid  = threadIdx.x >> 6;
  const int lane = threadIdx.x & 63;
  const int n = blockIdx.x*4 + wid;
  if (n >= N) return;
  const int beg = __builtin_amdgcn_readfirstlane(offsets[n]);
  const int end = __builtin_amdgcn_readfirstlane(offsets[n+1]);
  const int deg = end - beg;
  const int grp = lane >> 4, d4 = lane & 15;
  const int h0 = 2*grp, h1 = 2*grp + 1;

  // q fragments: 8 dims of heads h0,h1 at dims d4*8..+8
  const ushort* qtp = (const ushort*)qt + (size_t)n*1024 + d4*8;
  const uint4 Qa = *(const uint4*)(qtp + h0*128);
  const uint4 Qb = *(const uint4*)(qtp + h1*128);
  const float4 q0lo = make_float4(blo(Qa.x), bhi(Qa.x), blo(Qa.y), bhi(Qa.y));
  const float4 q0hi = make_float4(blo(Qa.z), bhi(Qa.z), blo(Qa.w), bhi(Qa.w));
  const float4 q1lo = make_float4(blo(Qb.x), bhi(Qb.x), blo(Qb.y), bhi(Qb.y));
  const float4 q1hi = make_float4(blo(Qb.z), bhi(Qb.z), blo(Qb.w), bhi(Qb.w));
  const float SC = 0.12751744886681336f;           // log2(e)/sqrt(128)
  const float qs0 = qb[(size_t)n*8 + h0] * SC;
  const float qs1 = qb[(size_t)n*8 + h1] * SC;

  const int* rp = ridx + beg;

  float den0 = 0.f, den1 = 0.f;
  float4 x0lo = make_float4(0,0,0,0), x0hi = x0lo, x1lo = x0lo, x1hi = x0lo;

  if (deg > 0){
#define LOADP(Pa0, Pa1, Pb0, Pb1, base) do { \
    int iA = (base) < deg ? (base) : deg-1; \
    int iB = (base)+1 < deg ? (base)+1 : deg-1; \
    const float4* pA = (const float4*)(ast + (size_t)rp[iA]*128 + d4*8); \
    const float4* pB = (const float4*)(ast + (size_t)rp[iB]*128 + d4*8); \
    Pa0 = pA[0]; Pa1 = pA[1]; Pb0 = pB[0]; Pb1 = pB[1]; } while(0)

#define C1(A0, A1) do { \
    float s0, s1; \
    s0 = A0.x*q0lo.x; s0 = fmaf(A0.y, q0lo.y, s0); s0 = fmaf(A0.z, q0lo.z, s0); s0 = fmaf(A0.w, q0lo.w, s0); \
    s0 = fmaf(A1.x, q0hi.x, s0); s0 = fmaf(A1.y, q0hi.y, s0); s0 = fmaf(A1.z, q0hi.z, s0); s0 = fmaf(A1.w, q0hi.w, s0); \
    s1 = A0.x*q1lo.x; s1 = fmaf(A0.y, q1lo.y, s1); s1 = fmaf(A0.z, q1lo.z, s1); s1 = fmaf(A0.w, q1lo.w, s1); \
    s1 = fmaf(A1.x, q1hi.x, s1); s1 = fmaf(A1.y, q1hi.y, s1); s1 = fmaf(A1.z, q1hi.z, s1); s1 = fmaf(A1.w, q1hi.w, s1); \
    s0 = row16_sum(s0); s1 = row16_sum(s1); \
    const float p0 = exp2f(fmaf(s0, SC, qs0)); \
    const float p1 = exp2f(fmaf(s1, SC, qs1)); \
    den0 += p0; den1 += p1; \
    x0lo.x = fmaf(p0, A0.x, x0lo.x); x0lo.y = fmaf(p0, A0.y, x0lo.y); \
    x0lo.z = fmaf(p0, A0.z, x0lo.z); x0lo.w = fmaf(p0, A0.w, x0lo.w); \
    x0hi.x = fmaf(p0, A1.x, x0hi.x); x0hi.y = fmaf(p0, A1.y, x0hi.y); \
    x0hi.z = fmaf(p0, A1.z, x0hi.z); x0hi.w = fmaf(p0, A1.w, x0hi.w); \
    x1lo.x = fmaf(p1, A0.x, x1lo.x); x1lo.y = fmaf(p1, A0.y, x1lo.y); \
    x1lo.z = fmaf(p1, A0.z, x1lo.z); x1lo.w = fmaf(p1, A0.w, x1lo.w); \
    x1hi.x = fmaf(p1, A1.x, x1hi.x); x1hi.y = fmaf(p1, A1.y, x1hi.y); \
    x1hi.z = fmaf(p1, A1.z, x1hi.z); x1hi.w = fmaf(p1, A1.w, x1hi.w); \
  } while(0)

    float4 P0a0, P0a1, P0b0, P0b1;
    float4 P1a0, P1a1, P1b0, P1b1;
    float4 P2a0, P2a1, P2b0, P2b1;
    LOADP(P0a0, P0a1, P0b0, P0b1, 0);
    LOADP(P1a0, P1a1, P1b0, P1b1, 2);
    LOADP(P2a0, P2a1, P2b0, P2b1, 4);
    int e = 0;
    for (; e + 5 < deg; e += 6){
      C1(P0a0, P0a1); C1(P0b0, P0b1); LOADP(P0a0, P0a1, P0b0, P0b1, e + 6);
      C1(P1a0, P1a1); C1(P1b0, P1b1); LOADP(P1a0, P1a1, P1b0, P1b1, e + 8);
      C1(P2a0, P2a1); C1(P2b0, P2b1); LOADP(P2a0, P2a1, P2b0, P2b1, e + 10);
    }
    const int t = deg - e;   // 1..6
    if (t >= 1) C1(P0a0, P0a1);
    if (t >= 2) C1(P0b0, P0b1);
    if (t >= 3) C1(P1a0, P1a1);
    if (t >= 4) C1(P1b0, P1b1);
    if (t >= 5) C1(P2a0, P2a1);
    if (t >= 6) C1(P2b0, P2b1);
#undef C1
#undef LOADP
  }
  const float r0v = (deg > 0) ? (1.f / den0) : 0.f;
  const float r1v = (deg > 0) ? (1.f / den1) : 0.f;

  uint4 o0, o1;
  o0.x = pack2(x0lo.x*r0v, x0lo.y*r0v); o0.y = pack2(x0lo.z*r0v, x0lo.w*r0v);
  o0.z = pack2(x0hi.x*r0v, x0hi.y*r0v); o0.w = pack2(x0hi.z*r0v, x0hi.w*r0v);
  o1.x = pack2(x1lo.x*r1v, x1lo.y*r1v); o1.y = pack2(x1lo.z*r1v, x1lo.w*r1v);
  o1.z = pack2(x1hi.x*r1v, x1hi.y*r1v); o1.w = pack2(x1hi.z*r1v, x1hi.w*r1v);
  ushort* hb = (ushort*)ho + (size_t)n*1024 + d4*8;
  *(uint4*)(hb + h0*128) = o0;
  *(uint4*)(hb + h1*128) = o1;
}

// ---------------- K5: out[n][c] = sum_k ho[n][k]*Wo[k][c] + bo[c]  via bf16 MFMA, split-Wo.
__global__ __launch_bounds__(256, 1) void out_mfma(const bf16* __restrict__ ho, const uint4* __restrict__ Wp,
                                                   const float* __restrict__ bo, float* __restrict__ out, int N){
  const int l = threadIdx.x & 63, w = threadIdx.x >> 6;
  const int lr = l & 15, lk = l >> 4;
  const int r0 = blockIdx.x*128 + w*32;
  int ra = r0 + lr;      if (ra > N-1) ra = N-1;
  int rb = r0 + 16 + lr; if (rb > N-1) rb = N-1;
  const bf16* pa = ho + (size_t)ra*1024 + lk*8;
  const bf16* pb = ho + (size_t)rb*1024 + lk*8;
  const uint4* pw = Wp + l;

  f32x4 acc[2][8];
  #pragma unroll
  for (int i = 0; i < 2; ++i)
    #pragma unroll
    for (int c = 0; c < 8; ++c)
      #pragma unroll
      for (int j = 0; j < 4; ++j) acc[i][c][j] = 0.f;

  bf16x8 Aa[2], Ab[2], Ba[16], Bb[16];

  auto LD = [&](int ks, bf16x8* A, bf16x8* B){
    A[0] = *(const bf16x8*)(pa + ks*32);
    A[1] = *(const bf16x8*)(pb + ks*32);
    const uint4* q = pw + (size_t)ks*1024;
    #pragma unroll
    for (int u = 0; u < 16; ++u) B[u] = *(const bf16x8*)(q + (size_t)u*64);
  };
  auto MM = [&](bf16x8* A, bf16x8* B){
    #pragma unroll
    for (int c = 0; c < 8; ++c){
      acc[0][c] = __builtin_amdgcn_mfma_f32_16x16x32_bf16(A[0], B[2*c],   acc[0][c], 0, 0, 0);
      acc[1][c] = __builtin_amdgcn_mfma_f32_16x16x32_bf16(A[1], B[2*c],   acc[1][c], 0, 0, 0);
      acc[0][c] = __builtin_amdgcn_mfma_f32_16x16x32_bf16(A[0], B[2*c+1], acc[0][c], 0, 0, 0);
      acc[1][c] = __builtin_amdgcn_mfma_f32_16x16x32_bf16(A[1], B[2*c+1], acc[1][c], 0, 0, 0);
    }
  };

  LD(0, Aa, Ba);
  for (int ks = 0; ks < 32; ks += 2){
    LD(ks + 1, Ab, Bb);
    MM(Aa, Ba);
    if (ks + 2 < 32) LD(ks + 2, Aa, Ba);
    MM(Ab, Bb);
  }

  #pragma unroll
  for (int c = 0; c < 8; ++c){
    float bv = bo[c*16 + lr];
    #pragma unroll
    for (int rt = 0; rt < 2; ++rt){
      #pragma unroll
      for (int i = 0; i < 4; ++i){
        int rr = r0 + rt*16 + lk*4 + i;
        if (rr < N) out[(size_t)rr*128 + c*16 + lr] = acc[rt][c][i] + bv;
      }
    }
  }
}

extern "C" void kernel_launch(void* const* d_in, const int* in_sizes, int n_in,
                              void* d_out, int out_size, void* d_ws, size_t ws_size,
                              hipStream_t stream) {
  const float* ast = (const float*)d_in[0];
  const float* Wq  = (const float*)d_in[1];
  const float* bq  = (const float*)d_in[2];
  const float* Wk  = (const float*)d_in[3];
  const float* bk  = (const float*)d_in[4];
  const float* Wo  = (const float*)d_in[5];
  const float* bo  = (const float*)d_in[6];
  const int* ast_key   = (const int*)d_in[7];
  const int* ast_value = (const int*)d_in[8];
  const int* pdg_key   = (const int*)d_in[9];
  const int* pdg_value = (const int*)d_in[10];
  const int E     = in_sizes[7];
  const int n_map = in_sizes[9];
  const int N     = out_size / 128;
  float* out = (float*)d_out;   // reference output dtype is float32

  char* w = (char*)d_ws;
  auto carve = [&](size_t bytes)->char*{
    char* p = w; w += (bytes + 255) & ~size_t(255); return p;
  };
  bf16*  qt      = (bf16*) carve((size_t)N*1024*2);
  float* aq      = (float*)carve((size_t)N*128*4);
  float* Mb      = (float*)carve((size_t)128*1024*4);
  float* cvec    = (float*)carve(1024*4);
  float* uvec    = (float*)carve(1024*4);
  float* sv      = (float*)carve(8*4);
  float* qb      = (float*)carve((size_t)N*8*4);
  int*   counts  = (int*)  carve((size_t)N*4);
  int*   offsets = (int*)  carve((size_t)(N+1)*4);
  int*   cursor  = (int*)  carve((size_t)N*4);
  int*   ridx    = (int*)  carve((size_t)E*4);
  bf16*  ho      = (bf16*) carve((size_t)N*1024*2);
  uint4* Wp      = (uint4*)carve((size_t)256*2*64*16);   // 512 KB packed WoHi/WoLo frags
  ushort* aqh    = (ushort*)carve((size_t)N*128*2);
  ushort* aql    = (ushort*)carve((size_t)N*128*2);
  uint4* Mp      = (uint4*)carve((size_t)256*2*64*16);   // 512 KB packed MbHi/MbLo frags
  (void)ws_size; (void)n_in;

  hipMemsetAsync(aq,     0, (size_t)N*128*4, stream);
  hipMemsetAsync(aqh,    0, (size_t)N*128*2, stream);
  hipMemsetAsync(aql,    0, (size_t)N*128*2, stream);
  hipMemsetAsync(counts, 0, (size_t)N*4, stream);
  hipMemsetAsync(cursor, 0, (size_t)N*4, stream);

  build_M   <<<64, 256, 0, stream>>>(Wq, Wk, Mb);
  build_bias<<<8, 128, 0, stream>>>(Wq, Wk, bq, bk, cvec, uvec, sv);
  frag_pack <<<256, 64, 0, stream>>>(Wo, Wp, 128, 8);    // K=1024, C=128
  scatter_aq<<<n_map, 64, 0, stream>>>(pdg_key, pdg_value, ast, aq, aqh, aql, n_map);
  frag_pack <<<256, 64, 0, stream>>>(Mb, Mp, 1024, 64);  // K=128,  C=1024
  qt_mfma   <<<(N + 127)/128, 256, 0, stream>>>(aqh, aql, Mp, cvec, qt, N);
  qb_kernel <<<N, 64, 0, stream>>>(aq, uvec, sv, qb);
  count_edges<<<(E + 255)/256, 256, 0, stream>>>(ast_value, counts, E);
  scan_offsets<<<1, 1024, 0, stream>>>(counts, offsets, N);
  fill_edges<<<(E + 255)/256, 256, 0, stream>>>(ast_value, ast_key, offsets, cursor, ridx, E);
  seg_attn  <<<(N + 3)/4, 256, 0, stream>>>(qt, qb, offsets, ridx, ast, ho, N);
  out_mfma  <<<(N + 127)/128, 256, 0, stream>>>(ho, Wp, bo, out, N);
}